// Round 1
// baseline (13293.219 us; speedup 1.0000x reference)
//
#include <hip/hip_runtime.h>
#include <cstddef>

// Problem constants
constexpr int kB  = 128;   // batch
constexpr int kT  = 32;    // time steps
constexpr int kN  = 196;   // attention positions
constexpr int kE  = 1024;  // embed dim
constexpr int kFD = 1024;  // feature dim
constexpr int kH  = 1024;  // hidden
constexpr int kA  = 1024;  // attention dim
constexpr int kG4 = 4096;  // 4*H

__device__ __forceinline__ float fsigmoid(float x) { return 1.f / (1.f + __expf(-x)); }
__device__ __forceinline__ float ftanh(float x)    { return 1.f - 2.f / (__expf(2.f * x) + 1.f); }

// ---------------------------------------------------------------------------
// Generic NN GEMM: C[M,Nc] (+= via K-split partials) = X[M,Kfull] @ W[Kfull,Nc] + bias
// 64x64 tile, KT=16, 256 threads, 4x4 per thread. blockIdx.z = K-split chunk:
// koff = bz*Klen, C written at C + bz*M*Nc (no atomics; consumer sums chunks).
// ---------------------------------------------------------------------------
__global__ __launch_bounds__(256) void gemm_nn_bias(
    const float* __restrict__ Xm, const float* __restrict__ Wm,
    const float* __restrict__ bias, float* __restrict__ C,
    int M, int Kfull, int Nc, int Klen)
{
    __shared__ __align__(16) float As[16][68];  // [k][m]
    __shared__ __align__(16) float Bs[16][68];  // [k][n]

    const int tid = threadIdx.x;
    const int bx = blockIdx.x, by = blockIdx.y, bz = blockIdx.z;
    const int m0 = bx * 64, n0 = by * 64;
    const int koff = bz * Klen;
    float* Cp = C + (size_t)bz * M * Nc;

    const int tx = tid & 15, ty = tid >> 4;
    // staging roles
    const int sr = tid & 63;       // A: m row
    const int sq = tid >> 6;       // A: k quad (4 floats)
    const int br = tid >> 4;       // B: k row (0..15)
    const int bc = (tid & 15) * 4; // B: n col

    float acc[4][4] = {{0.f,0.f,0.f,0.f},{0.f,0.f,0.f,0.f},{0.f,0.f,0.f,0.f},{0.f,0.f,0.f,0.f}};

    for (int k0 = 0; k0 < Klen; k0 += 16) {
        // stage A tile: rows m0..m0+63, cols koff+k0..+15
        {
            float4 av = *(const float4*)(Xm + (size_t)(m0 + sr) * Kfull + koff + k0 + sq * 4);
            As[sq * 4 + 0][sr] = av.x;
            As[sq * 4 + 1][sr] = av.y;
            As[sq * 4 + 2][sr] = av.z;
            As[sq * 4 + 3][sr] = av.w;
        }
        // stage B tile: rows koff+k0..+15, cols n0..n0+63
        {
            float4 bv = *(const float4*)(Wm + (size_t)(koff + k0 + br) * Nc + n0 + bc);
            *(float4*)&Bs[br][bc] = bv;
        }
        __syncthreads();
#pragma unroll
        for (int kk = 0; kk < 16; ++kk) {
            const float4 a4 = *(const float4*)&As[kk][ty * 4];
            const float4 b4 = *(const float4*)&Bs[kk][tx * 4];
            acc[0][0] += a4.x * b4.x; acc[0][1] += a4.x * b4.y; acc[0][2] += a4.x * b4.z; acc[0][3] += a4.x * b4.w;
            acc[1][0] += a4.y * b4.x; acc[1][1] += a4.y * b4.y; acc[1][2] += a4.y * b4.z; acc[1][3] += a4.y * b4.w;
            acc[2][0] += a4.z * b4.x; acc[2][1] += a4.z * b4.y; acc[2][2] += a4.z * b4.z; acc[2][3] += a4.z * b4.w;
            acc[3][0] += a4.w * b4.x; acc[3][1] += a4.w * b4.y; acc[3][2] += a4.w * b4.z; acc[3][3] += a4.w * b4.w;
        }
        __syncthreads();
    }

#pragma unroll
    for (int i = 0; i < 4; ++i) {
        const int m = m0 + ty * 4 + i;
        float4 r;
        r.x = acc[i][0]; r.y = acc[i][1]; r.z = acc[i][2]; r.w = acc[i][3];
        if (bias) {
            const float4 bv = *(const float4*)(bias + n0 + tx * 4);
            r.x += bv.x; r.y += bv.y; r.z += bv.z; r.w += bv.w;
        }
        *(float4*)(Cp + (size_t)m * Nc + n0 + tx * 4) = r;
    }
}

// ---------------------------------------------------------------------------
// scores[b,n] = sum_a tanh(fproj[b,n,a] + hwh[b,a]) * v[a]
// hwh = sum of 4 K-split partials. grid (B, 7); 4 waves x 7 n each = 28 n/block.
// ---------------------------------------------------------------------------
__global__ __launch_bounds__(256) void scores_kernel(
    const float* __restrict__ fproj, const float* __restrict__ hwhp,
    const float* __restrict__ vvec, float* __restrict__ scores)
{
    __shared__ float hwh_s[kA];
    __shared__ float v_s[kA];
    const int b = blockIdx.x, chunk = blockIdx.y;
    const int tid = threadIdx.x;

    for (int a = tid; a < kA; a += 256) {
        const size_t o = (size_t)b * kA + a;
        hwh_s[a] = hwhp[o] + hwhp[(size_t)kB * kA + o] +
                   hwhp[2 * (size_t)kB * kA + o] + hwhp[3 * (size_t)kB * kA + o];
        v_s[a] = vvec[a];
    }
    __syncthreads();

    const int wave = tid >> 6, lane = tid & 63;
#pragma unroll
    for (int i = 0; i < 7; ++i) {
        const int n = chunk * 28 + wave * 7 + i;
        const float* fp = fproj + ((size_t)b * kN + n) * kA;
        float p = 0.f;
        for (int a = lane; a < kA; a += 64)
            p += ftanh(fp[a] + hwh_s[a]) * v_s[a];
#pragma unroll
        for (int off = 32; off; off >>= 1) p += __shfl_down(p, off);
        if (lane == 0) scores[b * kN + n] = p;
    }
}

// softmax over N=196 per batch row. grid (B), block 256.
__global__ __launch_bounds__(256) void softmax_kernel(
    const float* __restrict__ scores, float* __restrict__ alpha)
{
    __shared__ float red[8];
    const int b = blockIdx.x, tid = threadIdx.x;
    const float val = (tid < kN) ? scores[b * kN + tid] : -1e30f;
    float m = val;
#pragma unroll
    for (int off = 32; off; off >>= 1) m = fmaxf(m, __shfl_down(m, off));
    if ((tid & 63) == 0) red[tid >> 6] = m;
    __syncthreads();
    m = fmaxf(fmaxf(red[0], red[1]), fmaxf(red[2], red[3]));
    const float e = (tid < kN) ? __expf(val - m) : 0.f;
    float s = e;
#pragma unroll
    for (int off = 32; off; off >>= 1) s += __shfl_down(s, off);
    if ((tid & 63) == 0) red[4 + (tid >> 6)] = s;
    __syncthreads();
    s = red[4] + red[5] + red[6] + red[7];
    if (tid < kN) alpha[b * kN + tid] = e * (1.f / s);
}

// attn[b,f] = sum_n alpha[b,n] * feats[b,n,f]. grid (B, 4), f = by*256+tid.
__global__ __launch_bounds__(256) void attn_kernel(
    const float* __restrict__ alpha, const float* __restrict__ feats,
    float* __restrict__ attn)
{
    __shared__ float al[kN + 4];
    const int b = blockIdx.x;
    const int f = blockIdx.y * 256 + threadIdx.x;
    if (threadIdx.x < kN) al[threadIdx.x] = alpha[b * kN + threadIdx.x];
    __syncthreads();
    const float* fb = feats + (size_t)b * kN * kFD + f;
    float acc = 0.f;
#pragma unroll 4
    for (int n = 0; n < kN; ++n) acc += al[n] * fb[(size_t)n * kFD];
    attn[b * kFD + f] = acc;
}

// W1sum = W_ih1 + W_hh1 (elementwise)
__global__ __launch_bounds__(256) void add_w_kernel(
    const float* __restrict__ a, const float* __restrict__ b,
    float* __restrict__ c, int n)
{
    const int i = blockIdx.x * 256 + threadIdx.x;
    if (i < n) c[i] = a[i] + b[i];
}

// ---------------------------------------------------------------------------
// Fused gates GEMM + LSTM cell.
// mode 0: gates = [emb_t|attn|h_cur] @ [Wih0|Whh0]^T (K=3072), cell(c_cur) -> h_next,c_next
// mode 1: gates = h0n @ W1sum^T (K=1024), cell(c0n) -> out[:,t,:] (h only)
// Tile: 64 b x 16 u x 4 gates per block; grid (2, 64); 256 threads.
// Thread: (ul = tid&15, b0 = tid>>4) computes 4 b x 4 gates for one u.
// ---------------------------------------------------------------------------
__global__ __launch_bounds__(256) void gates_cell_kernel(
    int mode, int tstep,
    const float* __restrict__ emb, const float* __restrict__ attn,
    const float* __restrict__ hsrc,
    const float* __restrict__ W0a, const float* __restrict__ W0b,
    const float* __restrict__ bia, const float* __restrict__ bib,
    const float* __restrict__ c_in,
    float* __restrict__ h_out, float* __restrict__ c_out,
    float* __restrict__ outp)
{
    __shared__ __align__(16) float xs[32][68];     // [kk][b], padded
    __shared__ __align__(16) float ws2[16 * 132];  // [ul][kk*4+g], padded stride 132

    const int tid = threadIdx.x;
    const int bx = blockIdx.x, by = blockIdx.y;
    const int u0 = by * 16;
    const int Ktot = (mode == 0) ? 3072 : 1024;

    const int ul = tid & 15, b0 = tid >> 4;
    // staging roles: r = lane row, q = k-octet (uniform per wave)
    const int sr = tid & 63;
    const int kq = (tid >> 6) * 8;

    float acc[4][4] = {{0.f,0.f,0.f,0.f},{0.f,0.f,0.f,0.f},{0.f,0.f,0.f,0.f},{0.f,0.f,0.f,0.f}};

    for (int k0 = 0; k0 < Ktot; k0 += 32) {
        // ---- stage X tile: 64 b x 32 k (source select is block-uniform) ----
        {
            const int b_g = bx * 64 + sr;
            const int k = k0 + kq;
            const float* src;
            if (mode == 0) {
                if (k0 < 1024)       src = emb  + ((size_t)b_g * kT + tstep) * kE + k;
                else if (k0 < 2048)  src = attn + (size_t)b_g * kFD + (k - 1024);
                else                 src = hsrc + (size_t)b_g * kH  + (k - 2048);
            } else {
                src = hsrc + (size_t)b_g * kH + k;
            }
            const float4 x0 = *(const float4*)(src);
            const float4 x1 = *(const float4*)(src + 4);
            xs[kq + 0][sr] = x0.x; xs[kq + 1][sr] = x0.y; xs[kq + 2][sr] = x0.z; xs[kq + 3][sr] = x0.w;
            xs[kq + 4][sr] = x1.x; xs[kq + 5][sr] = x1.y; xs[kq + 6][sr] = x1.z; xs[kq + 7][sr] = x1.w;
        }
        // ---- stage W tile: 64 rows (16 u x 4 gates) x 32 k ----
        {
            const int g = sr >> 4, ulr = sr & 15;
            const int j = g * 1024 + u0 + ulr;
            const int k = k0 + kq;
            const float* wsrc;
            if (mode == 0) {
                if (k0 < 2048) wsrc = W0a + (size_t)j * 2048 + k;
                else           wsrc = W0b + (size_t)j * 1024 + (k - 2048);
            } else {
                wsrc = W0a + (size_t)j * 1024 + k;
            }
            const float4 w0 = *(const float4*)(wsrc);
            const float4 w1 = *(const float4*)(wsrc + 4);
            float* wp = &ws2[ulr * 132];
            wp[(kq + 0) * 4 + g] = w0.x; wp[(kq + 1) * 4 + g] = w0.y;
            wp[(kq + 2) * 4 + g] = w0.z; wp[(kq + 3) * 4 + g] = w0.w;
            wp[(kq + 4) * 4 + g] = w1.x; wp[(kq + 5) * 4 + g] = w1.y;
            wp[(kq + 6) * 4 + g] = w1.z; wp[(kq + 7) * 4 + g] = w1.w;
        }
        __syncthreads();
#pragma unroll
        for (int kk = 0; kk < 32; ++kk) {
            const float4 xv = *(const float4*)&xs[kk][b0 * 4];
            const float4 wv = *(const float4*)&ws2[ul * 132 + kk * 4];
            acc[0][0] += xv.x * wv.x; acc[0][1] += xv.x * wv.y; acc[0][2] += xv.x * wv.z; acc[0][3] += xv.x * wv.w;
            acc[1][0] += xv.y * wv.x; acc[1][1] += xv.y * wv.y; acc[1][2] += xv.y * wv.z; acc[1][3] += xv.y * wv.w;
            acc[2][0] += xv.z * wv.x; acc[2][1] += xv.z * wv.y; acc[2][2] += xv.z * wv.z; acc[2][3] += xv.z * wv.w;
            acc[3][0] += xv.w * wv.x; acc[3][1] += xv.w * wv.y; acc[3][2] += xv.w * wv.z; acc[3][3] += xv.w * wv.w;
        }
        __syncthreads();
    }

    // ---- epilogue: LSTM cell (gate order i, f, g, o) ----
    const int u_g = u0 + ul;
    float bsum[4];
#pragma unroll
    for (int g = 0; g < 4; ++g) bsum[g] = bia[g * 1024 + u_g] + bib[g * 1024 + u_g];

#pragma unroll
    for (int i = 0; i < 4; ++i) {
        const int b_g = bx * 64 + b0 * 4 + i;
        const float iv = fsigmoid(acc[i][0] + bsum[0]);
        const float fv = fsigmoid(acc[i][1] + bsum[1]);
        const float gv = ftanh(acc[i][2] + bsum[2]);
        const float ov = fsigmoid(acc[i][3] + bsum[3]);
        const float cprev = c_in[(size_t)b_g * kH + u_g];
        const float cn = fv * cprev + iv * gv;
        const float hn = ov * ftanh(cn);
        if (mode == 0) {
            h_out[(size_t)b_g * kH + u_g] = hn;
            c_out[(size_t)b_g * kH + u_g] = cn;
        } else {
            outp[((size_t)b_g * kT + tstep) * kH + u_g] = hn;
        }
    }
}

// ---------------------------------------------------------------------------
extern "C" void kernel_launch(void* const* d_in, const int* in_sizes, int n_in,
                              void* d_out, int out_size, void* d_ws, size_t ws_size,
                              hipStream_t stream)
{
    const float* feats = (const float*)d_in[0];
    const float* emb   = (const float*)d_in[1];
    const float* Wf    = (const float*)d_in[2];
    const float* Wh    = (const float*)d_in[3];
    const float* b_att = (const float*)d_in[4];
    const float* vvec  = (const float*)d_in[5];
    const float* Wih0  = (const float*)d_in[6];
    const float* Whh0  = (const float*)d_in[7];
    const float* bih0  = (const float*)d_in[8];
    const float* bhh0  = (const float*)d_in[9];
    const float* Wih1  = (const float*)d_in[10];
    const float* Whh1  = (const float*)d_in[11];
    const float* bih1  = (const float*)d_in[12];
    const float* bhh1  = (const float*)d_in[13];
    float* out = (float*)d_out;
    float* ws  = (float*)d_ws;

    // workspace layout (floats); total ~31.1M floats ~ 119 MiB
    float* fproj  = ws;                                      // 25088*1024
    float* W1sum  = fproj  + (size_t)25088 * 1024;           // 4096*1024
    float* hwhp   = W1sum  + (size_t)4096 * 1024;            // 4*128*1024 (K-split partials)
    float* scores = hwhp   + (size_t)4 * 128 * 1024;         // 128*196
    float* alpha  = scores + 128 * 196;                      // 128*196
    float* attn   = alpha  + 128 * 196;                      // 128*1024
    float* hbuf   = attn   + 128 * 1024;                     // 2*128*1024
    float* cbuf   = hbuf   + 2 * 128 * 1024;                 // 2*128*1024

    // h0 = c0 = 0 (hbuf and cbuf are contiguous)
    hipMemsetAsync(hbuf, 0, sizeof(float) * 4 * 128 * 1024, stream);

    // W1sum = W_ih1 + W_hh1
    add_w_kernel<<<dim3((4096 * 1024) / 256), 256, 0, stream>>>(Wih1, Whh1, W1sum, 4096 * 1024);

    // f_proj = feats @ Wf + b_att   [25088, 1024]
    gemm_nn_bias<<<dim3(392, 16, 1), 256, 0, stream>>>(feats, Wf, b_att, fproj,
                                                       25088, 1024, 1024, 1024);

    for (int t = 0; t < kT; ++t) {
        float* h_cur = hbuf + (size_t)(t & 1) * 128 * 1024;
        float* h_nxt = hbuf + (size_t)((t + 1) & 1) * 128 * 1024;
        float* c_cur = cbuf + (size_t)(t & 1) * 128 * 1024;
        float* c_nxt = cbuf + (size_t)((t + 1) & 1) * 128 * 1024;

        // hWh partials: h_cur @ Wh, K split 4x256
        gemm_nn_bias<<<dim3(2, 16, 4), 256, 0, stream>>>(h_cur, Wh, nullptr, hwhp,
                                                         128, 1024, 1024, 256);
        scores_kernel<<<dim3(128, 7), 256, 0, stream>>>(fproj, hwhp, vvec, scores);
        softmax_kernel<<<dim3(128), 256, 0, stream>>>(scores, alpha);
        attn_kernel<<<dim3(128, 4), 256, 0, stream>>>(alpha, feats, attn);
        // layer 0: gates + cell -> h_nxt, c_nxt
        gates_cell_kernel<<<dim3(2, 64), 256, 0, stream>>>(
            0, t, emb, attn, h_cur, Wih0, Whh0, bih0, bhh0, c_cur, h_nxt, c_nxt, nullptr);
        // layer 1: gates (W1sum) + cell(c0n) -> out[:, t, :]
        gates_cell_kernel<<<dim3(2, 64), 256, 0, stream>>>(
            1, t, nullptr, nullptr, h_nxt, W1sum, nullptr, bih1, bhh1, c_nxt,
            nullptr, nullptr, out);
    }
    (void)in_sizes; (void)n_in; (void)out_size; (void)ws_size;
}

// Round 2
// 8468.974 us; speedup vs baseline: 1.5696x; 1.5696x over previous
//
#include <hip/hip_runtime.h>
#include <cstddef>

typedef unsigned short ushort_t;
typedef unsigned int uint_t;
typedef __attribute__((ext_vector_type(8))) short bf16x8;
typedef __attribute__((ext_vector_type(4))) float f32x4;

constexpr int kB  = 128;
constexpr int kT  = 32;
constexpr int kN  = 196;
constexpr int kE  = 1024;
constexpr int kFD = 1024;
constexpr int kH  = 1024;
constexpr int kA  = 1024;

__device__ __forceinline__ float fsigmoid(float x) { return 1.f / (1.f + __expf(-x)); }
__device__ __forceinline__ float ftanh(float x)    { return 1.f - 2.f / (__expf(2.f * x) + 1.f); }
__device__ __forceinline__ ushort_t f2bf(float f) {
    uint_t u = __float_as_uint(f);
    return (ushort_t)((u + 0x7fffu + ((u >> 16) & 1u)) >> 16);
}
__device__ __forceinline__ float bf2f(ushort_t h) {
    return __uint_as_float(((uint_t)h) << 16);
}

// ---------------------------------------------------------------------------
// fp32 GEMM (kept for hWh): C[M,Nc] = X[M,K] @ W[K,Nc], K-split partials.
// ---------------------------------------------------------------------------
__global__ __launch_bounds__(256) void gemm_nn_bias(
    const float* __restrict__ Xm, const float* __restrict__ Wm,
    const float* __restrict__ bias, float* __restrict__ C,
    int M, int Kfull, int Nc, int Klen)
{
    __shared__ __align__(16) float As[16][68];
    __shared__ __align__(16) float Bs[16][68];

    const int tid = threadIdx.x;
    const int bx = blockIdx.x, by = blockIdx.y, bz = blockIdx.z;
    const int m0 = bx * 64, n0 = by * 64;
    const int koff = bz * Klen;
    float* Cp = C + (size_t)bz * M * Nc;

    const int tx = tid & 15, ty = tid >> 4;
    const int sr = tid & 63;
    const int sq = tid >> 6;
    const int br = tid >> 4;
    const int bc = (tid & 15) * 4;

    float acc[4][4] = {{0.f,0.f,0.f,0.f},{0.f,0.f,0.f,0.f},{0.f,0.f,0.f,0.f},{0.f,0.f,0.f,0.f}};

    for (int k0 = 0; k0 < Klen; k0 += 16) {
        {
            float4 av = *(const float4*)(Xm + (size_t)(m0 + sr) * Kfull + koff + k0 + sq * 4);
            As[sq * 4 + 0][sr] = av.x;
            As[sq * 4 + 1][sr] = av.y;
            As[sq * 4 + 2][sr] = av.z;
            As[sq * 4 + 3][sr] = av.w;
        }
        {
            float4 bv = *(const float4*)(Wm + (size_t)(koff + k0 + br) * Nc + n0 + bc);
            *(float4*)&Bs[br][bc] = bv;
        }
        __syncthreads();
#pragma unroll
        for (int kk = 0; kk < 16; ++kk) {
            const float4 a4 = *(const float4*)&As[kk][ty * 4];
            const float4 b4 = *(const float4*)&Bs[kk][tx * 4];
            acc[0][0] += a4.x * b4.x; acc[0][1] += a4.x * b4.y; acc[0][2] += a4.x * b4.z; acc[0][3] += a4.x * b4.w;
            acc[1][0] += a4.y * b4.x; acc[1][1] += a4.y * b4.y; acc[1][2] += a4.y * b4.z; acc[1][3] += a4.y * b4.w;
            acc[2][0] += a4.z * b4.x; acc[2][1] += a4.z * b4.y; acc[2][2] += a4.z * b4.z; acc[2][3] += a4.z * b4.w;
            acc[3][0] += a4.w * b4.x; acc[3][1] += a4.w * b4.y; acc[3][2] += a4.w * b4.z; acc[3][3] += a4.w * b4.w;
        }
        __syncthreads();
    }

#pragma unroll
    for (int i = 0; i < 4; ++i) {
        const int m = m0 + ty * 4 + i;
        float4 r;
        r.x = acc[i][0]; r.y = acc[i][1]; r.z = acc[i][2]; r.w = acc[i][3];
        if (bias) {
            const float4 bv = *(const float4*)(bias + n0 + tx * 4);
            r.x += bv.x; r.y += bv.y; r.z += bv.z; r.w += bv.w;
        }
        *(float4*)(Cp + (size_t)m * Nc + n0 + tx * 4) = r;
    }
}

// ---------------------------------------------------------------------------
// Pre-pass casts
// ---------------------------------------------------------------------------
// W0bf[j][0..3071] = bf16([Wih0_row_j | Whh0_row_j]); one thread per 4 elems
__global__ __launch_bounds__(256) void cast_w0(
    const float* __restrict__ Wih0, const float* __restrict__ Whh0,
    ushort_t* __restrict__ W0bf)
{
    const int idx = blockIdx.x * 256 + threadIdx.x;       // 4096*768 total
    const int j = idx / 768;
    const int kq = (idx - j * 768) * 4;
    const float* src = (kq < 2048) ? (Wih0 + (size_t)j * 2048 + kq)
                                   : (Whh0 + (size_t)j * 1024 + (kq - 2048));
    const float4 v = *(const float4*)src;
    ushort4 h;
    h.x = f2bf(v.x); h.y = f2bf(v.y); h.z = f2bf(v.z); h.w = f2bf(v.w);
    *(ushort4*)&W0bf[(size_t)j * 3072 + kq] = h;
}

// W1bf = bf16(Wih1 + Whh1)
__global__ __launch_bounds__(256) void cast_w1(
    const float* __restrict__ Wih1, const float* __restrict__ Whh1,
    ushort_t* __restrict__ W1bf)
{
    const int idx = blockIdx.x * 256 + threadIdx.x;       // 4096*256 total
    const int off = idx * 4;
    const float4 a = *(const float4*)(Wih1 + off);
    const float4 b = *(const float4*)(Whh1 + off);
    ushort4 h;
    h.x = f2bf(a.x + b.x); h.y = f2bf(a.y + b.y);
    h.z = f2bf(a.z + b.z); h.w = f2bf(a.w + b.w);
    *(ushort4*)&W1bf[off] = h;
}

// WfT[a][k] = bf16(Wf[k][a])  (transposed cast, 64x64 LDS tiles)
__global__ __launch_bounds__(256) void wf_transpose(
    const float* __restrict__ Wf, ushort_t* __restrict__ WfT)
{
    __shared__ float t[64][65];
    const int k0 = blockIdx.x * 64, a0 = blockIdx.y * 64;
    const int c = threadIdx.x & 15, r0 = threadIdx.x >> 4;
#pragma unroll
    for (int i = 0; i < 4; ++i) {
        const int r = r0 + i * 16;
        const float4 v = *(const float4*)(Wf + (size_t)(k0 + r) * 1024 + a0 + c * 4);
        t[r][c * 4 + 0] = v.x; t[r][c * 4 + 1] = v.y;
        t[r][c * 4 + 2] = v.z; t[r][c * 4 + 3] = v.w;
    }
    __syncthreads();
#pragma unroll
    for (int i = 0; i < 4; ++i) {
        const int r = r0 + i * 16;   // a-local row
        ushort4 h;
        h.x = f2bf(t[c * 4 + 0][r]); h.y = f2bf(t[c * 4 + 1][r]);
        h.z = f2bf(t[c * 4 + 2][r]); h.w = f2bf(t[c * 4 + 3][r]);
        *(ushort4*)&WfT[(size_t)(a0 + r) * 1024 + k0 + c * 4] = h;
    }
}

// ---------------------------------------------------------------------------
// fproj = bf16(feats @ Wf + b_att) via MFMA 16x16x32 bf16.
// Tile 128x128, BK=32, 256 threads (4 waves, 2x2 of 64x64). A staged with
// in-flight fp32->bf16 convert; B from pre-cast WfT (n-major, k-contiguous).
// ---------------------------------------------------------------------------
__global__ __launch_bounds__(256) void fproj_mfma(
    const float* __restrict__ feats, const ushort_t* __restrict__ WfT,
    const float* __restrict__ bias, ushort_t* __restrict__ fprojbf)
{
    __shared__ ushort_t As[128 * 40];   // [row][k] pad to 40
    __shared__ ushort_t Bs[128 * 40];

    const int tid = threadIdx.x;
    const int m0 = blockIdx.x * 128, n0 = blockIdx.y * 128;
    const int lane = tid & 63, w = tid >> 6;
    const int wm = (w & 1) * 64, wn = (w >> 1) * 64;
    const int lr = lane & 15, quad = lane >> 4;

    f32x4 acc[4][4];
#pragma unroll
    for (int i = 0; i < 4; ++i)
#pragma unroll
        for (int j = 0; j < 4; ++j)
            acc[i][j] = (f32x4){0.f, 0.f, 0.f, 0.f};

    for (int k0 = 0; k0 < 1024; k0 += 32) {
        // stage A (fp32 -> bf16): 128 rows x 32 k = 1024 float4-quads
#pragma unroll
        for (int it = 0; it < 4; ++it) {
            const int q = it * 256 + tid;
            const int row = q >> 3, kc = (q & 7) * 4;
            const float4 v = *(const float4*)(feats + (size_t)(m0 + row) * 1024 + k0 + kc);
            ushort4 h;
            h.x = f2bf(v.x); h.y = f2bf(v.y); h.z = f2bf(v.z); h.w = f2bf(v.w);
            *(ushort4*)&As[row * 40 + kc] = h;
        }
        // stage B (already bf16): 128 rows x 32 k = 512 ushort8-chunks
#pragma unroll
        for (int it = 0; it < 2; ++it) {
            const int q = it * 256 + tid;
            const int row = q >> 2, kc = (q & 3) * 8;
            const uint4 v = *(const uint4*)(WfT + (size_t)(n0 + row) * 1024 + k0 + kc);
            *(uint4*)&Bs[row * 40 + kc] = v;
        }
        __syncthreads();

        bf16x8 af[4], bb[4];
#pragma unroll
        for (int mf = 0; mf < 4; ++mf)
            af[mf] = *(const bf16x8*)&As[(wm + mf * 16 + lr) * 40 + quad * 8];
#pragma unroll
        for (int nf = 0; nf < 4; ++nf)
            bb[nf] = *(const bf16x8*)&Bs[(wn + nf * 16 + lr) * 40 + quad * 8];
#pragma unroll
        for (int mf = 0; mf < 4; ++mf)
#pragma unroll
            for (int nf = 0; nf < 4; ++nf)
                acc[mf][nf] = __builtin_amdgcn_mfma_f32_16x16x32_bf16(
                    af[mf], bb[nf], acc[mf][nf], 0, 0, 0);
        __syncthreads();
    }

    // epilogue: D layout col=lane&15, row=quad*4+reg
#pragma unroll
    for (int nf = 0; nf < 4; ++nf) {
        const int n = n0 + wn + nf * 16 + lr;
        const float bn = bias[n];
#pragma unroll
        for (int mf = 0; mf < 4; ++mf) {
#pragma unroll
            for (int r = 0; r < 4; ++r) {
                const int m = m0 + wm + mf * 16 + quad * 4 + r;
                fprojbf[(size_t)m * 1024 + n] = f2bf(acc[mf][nf][r] + bn);
            }
        }
    }
}

// ---------------------------------------------------------------------------
// Fused scores + softmax + attn. grid(128)=b, 1024 threads (16 waves).
// hwh[b,:] (sum of 4 K-split partials) and v preloaded to 16 regs/lane.
// ---------------------------------------------------------------------------
__global__ __launch_bounds__(1024) void ssa_kernel(
    const ushort_t* __restrict__ fprojbf, const float* __restrict__ hwhp,
    const float* __restrict__ vvec, const float* __restrict__ feats,
    float* __restrict__ attn)
{
    __shared__ float scores_s[256];
    __shared__ float alpha_s[256];

    const int b = blockIdx.x;
    const int tid = threadIdx.x, lane = tid & 63, w = tid >> 6;

    // per-lane register slice: a = lane*16 + j
    float hw[16], vr[16];
    {
        const int a0 = lane * 16;
#pragma unroll
        for (int q = 0; q < 4; ++q) {
            const size_t o = (size_t)b * 1024 + a0 + q * 4;
            float4 s0 = *(const float4*)(hwhp + o);
            const float4 s1 = *(const float4*)(hwhp + 131072 + o);
            const float4 s2 = *(const float4*)(hwhp + 262144 + o);
            const float4 s3 = *(const float4*)(hwhp + 393216 + o);
            s0.x += s1.x + s2.x + s3.x; s0.y += s1.y + s2.y + s3.y;
            s0.z += s1.z + s2.z + s3.z; s0.w += s1.w + s2.w + s3.w;
            hw[q * 4 + 0] = s0.x; hw[q * 4 + 1] = s0.y;
            hw[q * 4 + 2] = s0.z; hw[q * 4 + 3] = s0.w;
            const float4 vv = *(const float4*)(vvec + a0 + q * 4);
            vr[q * 4 + 0] = vv.x; vr[q * 4 + 1] = vv.y;
            vr[q * 4 + 2] = vv.z; vr[q * 4 + 3] = vv.w;
        }
    }

    // scores: wave w handles n = w, w+16, ...
    for (int n = w; n < kN; n += 16) {
        const ushort_t* fp = fprojbf + ((size_t)(b * kN + n)) * 1024 + lane * 16;
        const uint4 u0 = *(const uint4*)(fp);
        const uint4 u1 = *(const uint4*)(fp + 8);
        float p = 0.f;
        const uint_t uu[8] = {u0.x, u0.y, u0.z, u0.w, u1.x, u1.y, u1.z, u1.w};
#pragma unroll
        for (int q = 0; q < 8; ++q) {
            const float xa = __uint_as_float(uu[q] << 16);
            const float xb = __uint_as_float(uu[q] & 0xffff0000u);
            p += ftanh(xa + hw[2 * q]) * vr[2 * q];
            p += ftanh(xb + hw[2 * q + 1]) * vr[2 * q + 1];
        }
#pragma unroll
        for (int off = 32; off; off >>= 1) p += __shfl_down(p, off);
        if (lane == 0) scores_s[n] = p;
    }
    __syncthreads();

    // softmax over 196, wave 0 only
    if (w == 0) {
        float x[4], e[4];
        float m = -1e30f;
#pragma unroll
        for (int k = 0; k < 4; ++k) {
            const int n = lane + 64 * k;
            x[k] = (n < kN) ? scores_s[n] : -1e30f;
            m = fmaxf(m, x[k]);
        }
#pragma unroll
        for (int off = 32; off; off >>= 1) m = fmaxf(m, __shfl_down(m, off));
        m = __shfl(m, 0);
        float s = 0.f;
#pragma unroll
        for (int k = 0; k < 4; ++k) {
            e[k] = (lane + 64 * k < kN) ? __expf(x[k] - m) : 0.f;
            s += e[k];
        }
#pragma unroll
        for (int off = 32; off; off >>= 1) s += __shfl_down(s, off);
        s = __shfl(s, 0);
        const float inv = 1.f / s;
#pragma unroll
        for (int k = 0; k < 4; ++k) {
            const int n = lane + 64 * k;
            if (n < kN) alpha_s[n] = e[k] * inv;
        }
    }
    __syncthreads();

    // attn: thread f = tid (1024 == FD)
    const float* fb = feats + (size_t)b * kN * kFD + tid;
    float a = 0.f;
#pragma unroll 4
    for (int n = 0; n < kN; ++n) a += alpha_s[n] * fb[(size_t)n * kFD];
    attn[(size_t)b * kFD + tid] = a;
}

// ---------------------------------------------------------------------------
// Gates GEMM (bf16 weights, fp32 x) + LSTM cell.
// mode 0: gates = [emb_t|attn|h_cur] @ W0bf^T (K=3072) -> h_next, c_next
// mode 1: gates = h0n @ W1bf^T (K=1024), cell(c0n) -> out[:,t,:]
// Tile: 32 b x 16 u x 4 gates; grid (4, 64); 256 threads; 2b x 4g per thread.
// ---------------------------------------------------------------------------
__global__ __launch_bounds__(256) void gates_cell_kernel(
    int mode, int tstep,
    const float* __restrict__ emb, const float* __restrict__ attn,
    const float* __restrict__ hsrc,
    const ushort_t* __restrict__ Wbf,
    const float* __restrict__ bia, const float* __restrict__ bib,
    const float* __restrict__ c_in,
    float* __restrict__ h_out, float* __restrict__ c_out,
    float* __restrict__ outp)
{
    __shared__ __align__(16) float xs[32][36];     // [kk][b]
    __shared__ __align__(16) float ws2[16 * 132];  // [ul][kk*4+g]

    const int tid = threadIdx.x;
    const int bx = blockIdx.x, by = blockIdx.y;
    const int u0 = by * 16;
    const int Ktot = (mode == 0) ? 3072 : 1024;
    const int Krow = Ktot;

    const int ul = tid & 15, b0 = tid >> 4;   // compute roles
    const int sr = tid & 31, kq = (tid >> 5) * 4;   // X staging
    const int wr = tid & 63, wq = (tid >> 6) * 8;   // W staging

    float acc[2][4] = {{0.f,0.f,0.f,0.f},{0.f,0.f,0.f,0.f}};

    for (int k0 = 0; k0 < Ktot; k0 += 32) {
        // ---- stage X tile: 32 b x 32 k (block-uniform source select) ----
        {
            const int b_g = bx * 32 + sr;
            const int k = k0 + kq;
            const float* src;
            if (mode == 0) {
                if (k0 < 1024)       src = emb  + ((size_t)b_g * kT + tstep) * kE + k;
                else if (k0 < 2048)  src = attn + (size_t)b_g * kFD + (k - 1024);
                else                 src = hsrc + (size_t)b_g * kH  + (k - 2048);
            } else {
                src = hsrc + (size_t)b_g * kH + k;
            }
            const float4 x0 = *(const float4*)(src);
            xs[kq + 0][sr] = x0.x; xs[kq + 1][sr] = x0.y;
            xs[kq + 2][sr] = x0.z; xs[kq + 3][sr] = x0.w;
        }
        // ---- stage W tile: 64 rows (16u x 4g) x 32 k, bf16 -> fp32 ----
        {
            const int g = wr >> 4, ulr = wr & 15;
            const int j = g * 1024 + u0 + ulr;
            const uint4 wv = *(const uint4*)(Wbf + (size_t)j * Krow + k0 + wq);
            const uint_t wu[4] = {wv.x, wv.y, wv.z, wv.w};
            float* wp = &ws2[ulr * 132];
#pragma unroll
            for (int q = 0; q < 4; ++q) {
                const float wlo = __uint_as_float(wu[q] << 16);
                const float whi = __uint_as_float(wu[q] & 0xffff0000u);
                wp[(wq + 2 * q + 0) * 4 + g] = wlo;
                wp[(wq + 2 * q + 1) * 4 + g] = whi;
            }
        }
        __syncthreads();
#pragma unroll
        for (int kk = 0; kk < 32; ++kk) {
            const float2 xv = *(const float2*)&xs[kk][b0 * 2];
            const float4 wv = *(const float4*)&ws2[ul * 132 + kk * 4];
            acc[0][0] += xv.x * wv.x; acc[0][1] += xv.x * wv.y;
            acc[0][2] += xv.x * wv.z; acc[0][3] += xv.x * wv.w;
            acc[1][0] += xv.y * wv.x; acc[1][1] += xv.y * wv.y;
            acc[1][2] += xv.y * wv.z; acc[1][3] += xv.y * wv.w;
        }
        __syncthreads();
    }

    // ---- epilogue: LSTM cell (gate order i, f, g, o) ----
    const int u_g = u0 + ul;
    float bsum[4];
#pragma unroll
    for (int g = 0; g < 4; ++g) bsum[g] = bia[g * 1024 + u_g] + bib[g * 1024 + u_g];

#pragma unroll
    for (int i = 0; i < 2; ++i) {
        const int b_g = bx * 32 + b0 * 2 + i;
        const float iv = fsigmoid(acc[i][0] + bsum[0]);
        const float fv = fsigmoid(acc[i][1] + bsum[1]);
        const float gv = ftanh(acc[i][2] + bsum[2]);
        const float ov = fsigmoid(acc[i][3] + bsum[3]);
        const float cprev = c_in[(size_t)b_g * kH + u_g];
        const float cn = fv * cprev + iv * gv;
        const float hn = ov * ftanh(cn);
        if (mode == 0) {
            h_out[(size_t)b_g * kH + u_g] = hn;
            c_out[(size_t)b_g * kH + u_g] = cn;
        } else {
            outp[((size_t)b_g * kT + tstep) * kH + u_g] = hn;
        }
    }
}

// ---------------------------------------------------------------------------
extern "C" void kernel_launch(void* const* d_in, const int* in_sizes, int n_in,
                              void* d_out, int out_size, void* d_ws, size_t ws_size,
                              hipStream_t stream)
{
    const float* feats = (const float*)d_in[0];
    const float* emb   = (const float*)d_in[1];
    const float* Wf    = (const float*)d_in[2];
    const float* Wh    = (const float*)d_in[3];
    const float* b_att = (const float*)d_in[4];
    const float* vvec  = (const float*)d_in[5];
    const float* Wih0  = (const float*)d_in[6];
    const float* Whh0  = (const float*)d_in[7];
    const float* bih0  = (const float*)d_in[8];
    const float* bhh0  = (const float*)d_in[9];
    const float* Wih1  = (const float*)d_in[10];
    const float* Whh1  = (const float*)d_in[11];
    const float* bih1  = (const float*)d_in[12];
    const float* bhh1  = (const float*)d_in[13];
    float* out = (float*)d_out;

    // workspace layout (bf16 arrays first, then fp32; all offsets 16B-aligned)
    ushort_t* fprojbf = (ushort_t*)d_ws;                      // 25088*1024
    ushort_t* W0bf    = fprojbf + (size_t)25088 * 1024;       // 4096*3072
    ushort_t* W1bf    = W0bf    + (size_t)4096 * 3072;        // 4096*1024
    ushort_t* WfT     = W1bf    + (size_t)4096 * 1024;        // 1024*1024
    float*    hwhp    = (float*)(WfT + (size_t)1024 * 1024);  // 4*128*1024
    float*    attn    = hwhp + (size_t)4 * 128 * 1024;        // 128*1024
    float*    hbuf    = attn + (size_t)128 * 1024;            // 2*128*1024
    float*    cbuf    = hbuf + (size_t)2 * 128 * 1024;        // 2*128*1024

    // h0 = c0 = 0
    hipMemsetAsync(hbuf, 0, sizeof(float) * 4 * 128 * 1024, stream);

    // pre-pass casts
    cast_w0<<<dim3(12288), 256, 0, stream>>>(Wih0, Whh0, W0bf);
    cast_w1<<<dim3(4096), 256, 0, stream>>>(Wih1, Whh1, W1bf);
    wf_transpose<<<dim3(16, 16), 256, 0, stream>>>(Wf, WfT);

    // fproj (bf16) = feats @ Wf + b_att
    fproj_mfma<<<dim3(196, 8), 256, 0, stream>>>(feats, WfT, b_att, fprojbf);

    for (int t = 0; t < kT; ++t) {
        float* h_cur = hbuf + (size_t)(t & 1) * 128 * 1024;
        float* h_nxt = hbuf + (size_t)((t + 1) & 1) * 128 * 1024;
        float* c_cur = cbuf + (size_t)(t & 1) * 128 * 1024;
        float* c_nxt = cbuf + (size_t)((t + 1) & 1) * 128 * 1024;

        gemm_nn_bias<<<dim3(2, 16, 4), 256, 0, stream>>>(h_cur, Wh, nullptr, hwhp,
                                                         128, 1024, 1024, 256);
        ssa_kernel<<<dim3(128), 1024, 0, stream>>>(fprojbf, hwhp, vvec, feats, attn);
        gates_cell_kernel<<<dim3(4, 64), 256, 0, stream>>>(
            0, t, emb, attn, h_cur, W0bf, bih0, bhh0, c_cur, h_nxt, c_nxt, nullptr);
        gates_cell_kernel<<<dim3(4, 64), 256, 0, stream>>>(
            1, t, nullptr, nullptr, h_nxt, W1bf, bih1, bhh1, c_nxt,
            nullptr, nullptr, out);
    }
    (void)in_sizes; (void)n_in; (void)out_size; (void)ws_size;
}

// Round 4
// 3655.055 us; speedup vs baseline: 3.6369x; 2.3171x over previous
//
#include <hip/hip_runtime.h>
#include <cstddef>

typedef unsigned short ushort_t;
typedef unsigned int uint_t;
typedef __attribute__((ext_vector_type(8))) short bf16x8;
typedef __attribute__((ext_vector_type(4))) float f32x4;

constexpr int kB  = 128;
constexpr int kT  = 32;
constexpr int kN  = 196;
constexpr int kH  = 1024;

__device__ __forceinline__ float fsigmoid(float x) { return 1.f / (1.f + __expf(-x)); }
__device__ __forceinline__ float ftanh(float x)    { return 1.f - 2.f / (__expf(2.f * x) + 1.f); }
__device__ __forceinline__ ushort_t f2bf(float f) {
    uint_t u = __float_as_uint(f);
    return (ushort_t)((u + 0x7fffu + ((u >> 16) & 1u)) >> 16);
}

// ---------------------------------------------------------------------------
// Pre-pass pack / cast kernels
// ---------------------------------------------------------------------------
// generic transposed cast: dst[a][k] = bf16(src[k][a]), 1024x1024
__global__ __launch_bounds__(256) void wf_transpose(
    const float* __restrict__ Wsrc, ushort_t* __restrict__ dst)
{
    __shared__ float t[64][65];
    const int k0 = blockIdx.x * 64, a0 = blockIdx.y * 64;
    const int c = threadIdx.x & 15, r0 = threadIdx.x >> 4;
#pragma unroll
    for (int i = 0; i < 4; ++i) {
        const int r = r0 + i * 16;
        const float4 v = *(const float4*)(Wsrc + (size_t)(k0 + r) * 1024 + a0 + c * 4);
        t[r][c * 4 + 0] = v.x; t[r][c * 4 + 1] = v.y;
        t[r][c * 4 + 2] = v.z; t[r][c * 4 + 3] = v.w;
    }
    __syncthreads();
#pragma unroll
    for (int i = 0; i < 4; ++i) {
        const int r = r0 + i * 16;
        ushort4 h;
        h.x = f2bf(t[c * 4 + 0][r]); h.y = f2bf(t[c * 4 + 1][r]);
        h.z = f2bf(t[c * 4 + 2][r]); h.w = f2bf(t[c * 4 + 3][r]);
        *(ushort4*)&dst[(size_t)(a0 + r) * 1024 + k0 + c * 4] = h;
    }
}

// Wbig rows 1024+j' (j'=u*4+g) <- bf16(Whh0[g*1024+u][k])
__global__ __launch_bounds__(256) void pack_whh0(
    const float* __restrict__ Whh0, ushort_t* __restrict__ Wbig)
{
    const int idx = blockIdx.x * 256 + threadIdx.x;  // 4096*256
    const int j = idx >> 8, k4 = (idx & 255) * 4;
    const int u = j >> 2, g = j & 3;
    const float4 v = *(const float4*)(Whh0 + (size_t)(g * 1024 + u) * 1024 + k4);
    ushort4 h;
    h.x = f2bf(v.x); h.y = f2bf(v.y); h.z = f2bf(v.z); h.w = f2bf(v.w);
    *(ushort4*)&Wbig[(size_t)(1024 + j) * 1024 + k4] = h;
}

// Wbig rows 5120+j' <- bf16(Wih1[g*1024+u][k] + Whh1[g*1024+u][k])
__global__ __launch_bounds__(256) void pack_w1sum(
    const float* __restrict__ Wih1, const float* __restrict__ Whh1,
    ushort_t* __restrict__ Wbig)
{
    const int idx = blockIdx.x * 256 + threadIdx.x;  // 4096*256
    const int j = idx >> 8, k4 = (idx & 255) * 4;
    const int u = j >> 2, g = j & 3;
    const size_t o = (size_t)(g * 1024 + u) * 1024 + k4;
    const float4 a = *(const float4*)(Wih1 + o);
    const float4 b = *(const float4*)(Whh1 + o);
    ushort4 h;
    h.x = f2bf(a.x + b.x); h.y = f2bf(a.y + b.y);
    h.z = f2bf(a.z + b.z); h.w = f2bf(a.w + b.w);
    *(ushort4*)&Wbig[(size_t)(5120 + j) * 1024 + k4] = h;
}

// W0cat[j'][k] : k<1024 -> attn cols (Wih0[.][1024+k]), else emb cols (Wih0[.][k-1024])
__global__ __launch_bounds__(256) void pack_w0cat(
    const float* __restrict__ Wih0, ushort_t* __restrict__ W0cat)
{
    const int idx = blockIdx.x * 256 + threadIdx.x;  // 4096*512
    const int j = idx >> 9, k4 = (idx & 511) * 4;
    const int u = j >> 2, g = j & 3;
    const int srccol = (k4 < 1024) ? (k4 + 1024) : (k4 - 1024);
    const float4 v = *(const float4*)(Wih0 + (size_t)(g * 1024 + u) * 2048 + srccol);
    ushort4 h;
    h.x = f2bf(v.x); h.y = f2bf(v.y); h.z = f2bf(v.z); h.w = f2bf(v.w);
    *(ushort4*)&W0cat[(size_t)j * 2048 + k4] = h;
}

// plain fp32 -> bf16 cast, 4 elems/thread
__global__ __launch_bounds__(256) void cast_bf(
    const float* __restrict__ src, ushort_t* __restrict__ dst)
{
    const size_t idx = ((size_t)blockIdx.x * 256 + threadIdx.x) * 4;
    const float4 v = *(const float4*)(src + idx);
    ushort4 h;
    h.x = f2bf(v.x); h.y = f2bf(v.y); h.z = f2bf(v.z); h.w = f2bf(v.w);
    *(ushort4*)&dst[idx] = h;
}

// ---------------------------------------------------------------------------
// fproj = bf16(feats @ Wf + b_att) via MFMA 16x16x32 bf16. 128x128 tile.
// ---------------------------------------------------------------------------
__global__ __launch_bounds__(256) void fproj_mfma(
    const float* __restrict__ feats, const ushort_t* __restrict__ WfT,
    const float* __restrict__ bias, ushort_t* __restrict__ fprojbf)
{
    __shared__ ushort_t As[128 * 40];
    __shared__ ushort_t Bs[128 * 40];

    const int tid = threadIdx.x;
    const int m0 = blockIdx.x * 128, n0 = blockIdx.y * 128;
    const int lane = tid & 63, w = tid >> 6;
    const int wm = (w & 1) * 64, wn = (w >> 1) * 64;
    const int lr = lane & 15, quad = lane >> 4;

    f32x4 acc[4][4];
#pragma unroll
    for (int i = 0; i < 4; ++i)
#pragma unroll
        for (int j = 0; j < 4; ++j)
            acc[i][j] = (f32x4){0.f, 0.f, 0.f, 0.f};

    for (int k0 = 0; k0 < 1024; k0 += 32) {
#pragma unroll
        for (int it = 0; it < 4; ++it) {
            const int q = it * 256 + tid;
            const int row = q >> 3, kc = (q & 7) * 4;
            const float4 v = *(const float4*)(feats + (size_t)(m0 + row) * 1024 + k0 + kc);
            ushort4 h;
            h.x = f2bf(v.x); h.y = f2bf(v.y); h.z = f2bf(v.z); h.w = f2bf(v.w);
            *(ushort4*)&As[row * 40 + kc] = h;
        }
#pragma unroll
        for (int it = 0; it < 2; ++it) {
            const int q = it * 256 + tid;
            const int row = q >> 2, kc = (q & 3) * 8;
            const uint4 v = *(const uint4*)(WfT + (size_t)(n0 + row) * 1024 + k0 + kc);
            *(uint4*)&Bs[row * 40 + kc] = v;
        }
        __syncthreads();

        bf16x8 af[4], bb[4];
#pragma unroll
        for (int mf = 0; mf < 4; ++mf)
            af[mf] = *(const bf16x8*)&As[(wm + mf * 16 + lr) * 40 + quad * 8];
#pragma unroll
        for (int nf = 0; nf < 4; ++nf)
            bb[nf] = *(const bf16x8*)&Bs[(wn + nf * 16 + lr) * 40 + quad * 8];
#pragma unroll
        for (int mf = 0; mf < 4; ++mf)
#pragma unroll
            for (int nf = 0; nf < 4; ++nf)
                acc[mf][nf] = __builtin_amdgcn_mfma_f32_16x16x32_bf16(
                    af[mf], bb[nf], acc[mf][nf], 0, 0, 0);
        __syncthreads();
    }

#pragma unroll
    for (int nf = 0; nf < 4; ++nf) {
        const int n = n0 + wn + nf * 16 + lr;
        const float bn = bias[n];
#pragma unroll
        for (int mf = 0; mf < 4; ++mf) {
#pragma unroll
            for (int r = 0; r < 4; ++r) {
                const int m = m0 + wm + mf * 16 + quad * 4 + r;
                fprojbf[(size_t)m * 1024 + n] = f2bf(acc[mf][nf][r] + bn);
            }
        }
    }
}

// ---------------------------------------------------------------------------
// Kernel A: Y = h_t(bf16) @ Wbig[9216,1024]^rowmajor.  Tile 128M x 64N, BK=32.
//   n0 <  1024 : hwh[b][n] (fp32)
//   n0 <  5120 : Ypart[b][n-1024] (fp32, unit-permuted j'=u*4+g)
//   n0 >= 5120 : gates1 (W1sum, unit-permuted) -> cell1(c) -> out[:,t-1,:]
// ---------------------------------------------------------------------------
__global__ __launch_bounds__(256) void hgemm_A(
    const ushort_t* __restrict__ hbf, const ushort_t* __restrict__ Wbig,
    const float* __restrict__ cbuf,
    const float* __restrict__ bih1, const float* __restrict__ bhh1,
    float* __restrict__ hwh, float* __restrict__ Ypart,
    float* __restrict__ out, int tstep)
{
    __shared__ ushort_t xs[128 * 40];
    __shared__ ushort_t wsB[64 * 40];
    __shared__ float eps[128][65];

    const int tid = threadIdx.x;
    const int n0 = blockIdx.x * 64;
    const int lane = tid & 63, w = tid >> 6;
    const int wm = (w & 1) * 64, wn = (w >> 1) * 32;
    const int lr = lane & 15, quad = lane >> 4;

    f32x4 acc[4][2];
#pragma unroll
    for (int i = 0; i < 4; ++i) {
        acc[i][0] = (f32x4){0.f, 0.f, 0.f, 0.f};
        acc[i][1] = (f32x4){0.f, 0.f, 0.f, 0.f};
    }

    for (int k0 = 0; k0 < 1024; k0 += 32) {
#pragma unroll
        for (int it = 0; it < 2; ++it) {
            const int q = it * 256 + tid;
            const int row = q >> 2, kc = (q & 3) * 8;
            *(uint4*)&xs[row * 40 + kc] =
                *(const uint4*)&hbf[(size_t)row * 1024 + k0 + kc];
        }
        {
            const int row = tid >> 2, kc = (tid & 3) * 8;
            *(uint4*)&wsB[row * 40 + kc] =
                *(const uint4*)&Wbig[(size_t)(n0 + row) * 1024 + k0 + kc];
        }
        __syncthreads();
        bf16x8 af[4], bb[2];
#pragma unroll
        for (int mf = 0; mf < 4; ++mf)
            af[mf] = *(const bf16x8*)&xs[(wm + mf * 16 + lr) * 40 + quad * 8];
#pragma unroll
        for (int nf = 0; nf < 2; ++nf)
            bb[nf] = *(const bf16x8*)&wsB[(wn + nf * 16 + lr) * 40 + quad * 8];
#pragma unroll
        for (int mf = 0; mf < 4; ++mf)
#pragma unroll
            for (int nf = 0; nf < 2; ++nf)
                acc[mf][nf] = __builtin_amdgcn_mfma_f32_16x16x32_bf16(
                    af[mf], bb[nf], acc[mf][nf], 0, 0, 0);
        __syncthreads();
    }

    if (n0 < 5120) {
        float* dst = (n0 < 1024) ? hwh : Ypart;
        const int stride = (n0 < 1024) ? 1024 : 4096;
        const int nbase = (n0 < 1024) ? n0 : (n0 - 1024);
#pragma unroll
        for (int mf = 0; mf < 4; ++mf)
#pragma unroll
            for (int nf = 0; nf < 2; ++nf)
#pragma unroll
                for (int r = 0; r < 4; ++r) {
                    const int m = wm + mf * 16 + quad * 4 + r;
                    const int n = nbase + wn + nf * 16 + lr;
                    dst[(size_t)m * stride + n] = acc[mf][nf][r];
                }
    } else {
#pragma unroll
        for (int mf = 0; mf < 4; ++mf)
#pragma unroll
            for (int nf = 0; nf < 2; ++nf)
#pragma unroll
                for (int r = 0; r < 4; ++r)
                    eps[wm + mf * 16 + quad * 4 + r][wn + nf * 16 + lr] = acc[mf][nf][r];
        __syncthreads();
        if (tstep >= 1) {
#pragma unroll
            for (int i = 0; i < 8; ++i) {
                const int cid = i * 256 + tid;
                const int b = cid & 127, ulc = cid >> 7;
                const int u = ((n0 - 5120) >> 2) + ulc;
                const float iv = fsigmoid(eps[b][ulc * 4 + 0] + bih1[u]        + bhh1[u]);
                const float fv = fsigmoid(eps[b][ulc * 4 + 1] + bih1[1024 + u] + bhh1[1024 + u]);
                const float gv = ftanh   (eps[b][ulc * 4 + 2] + bih1[2048 + u] + bhh1[2048 + u]);
                const float ov = fsigmoid(eps[b][ulc * 4 + 3] + bih1[3072 + u] + bhh1[3072 + u]);
                const float cp = cbuf[(size_t)b * 1024 + u];
                const float cn = fv * cp + iv * gv;
                out[((size_t)b * kT + (tstep - 1)) * 1024 + u] = ov * ftanh(cn);
            }
        }
    }
}

// ---------------------------------------------------------------------------
// scores[b,n] = sum_a tanh(fprojbf[b,n,a] + hwh[b,a]) * v[a].  grid (128,7).
// ---------------------------------------------------------------------------
__global__ __launch_bounds__(256) void scores_kernel(
    const ushort_t* __restrict__ fprojbf, const float* __restrict__ hwh,
    const float* __restrict__ vvec, float* __restrict__ scoresbuf)
{
    const int b = blockIdx.x, chunk = blockIdx.y;
    const int tid = threadIdx.x, lane = tid & 63, w = tid >> 6;

    float hw[16], vr[16];
    {
        const int a0 = lane * 16;
#pragma unroll
        for (int q = 0; q < 4; ++q) {
            const float4 s0 = *(const float4*)(hwh + (size_t)b * 1024 + a0 + q * 4);
            hw[q * 4 + 0] = s0.x; hw[q * 4 + 1] = s0.y;
            hw[q * 4 + 2] = s0.z; hw[q * 4 + 3] = s0.w;
            const float4 vv = *(const float4*)(vvec + a0 + q * 4);
            vr[q * 4 + 0] = vv.x; vr[q * 4 + 1] = vv.y;
            vr[q * 4 + 2] = vv.z; vr[q * 4 + 3] = vv.w;
        }
    }

#pragma unroll
    for (int i = 0; i < 7; ++i) {
        const int n = chunk * 28 + w * 7 + i;
        const ushort_t* fp = fprojbf + ((size_t)(b * kN + n)) * 1024 + lane * 16;
        const uint4 u0 = *(const uint4*)(fp);
        const uint4 u1 = *(const uint4*)(fp + 8);
        float p = 0.f;
        const uint_t uu[8] = {u0.x, u0.y, u0.z, u0.w, u1.x, u1.y, u1.z, u1.w};
#pragma unroll
        for (int q = 0; q < 8; ++q) {
            const float xa = __uint_as_float(uu[q] << 16);
            const float xb = __uint_as_float(uu[q] & 0xffff0000u);
            p += ftanh(xa + hw[2 * q]) * vr[2 * q];
            p += ftanh(xb + hw[2 * q + 1]) * vr[2 * q + 1];
        }
#pragma unroll
        for (int off = 32; off; off >>= 1) p += __shfl_down(p, off);
        if (lane == 0) scoresbuf[b * kN + n] = p;
    }
}

// ---------------------------------------------------------------------------
// softmax (per-block recompute) + attn -> attnbf.  BF=1: feats bf16, 2 f/thr,
// grid (128,2); BF=0: feats fp32, 1 f/thr, grid (128,4).
// ---------------------------------------------------------------------------
template<int BF>
__global__ __launch_bounds__(256) void attn_kernel(
    const float* __restrict__ scoresbuf, const float* __restrict__ featsf,
    const ushort_t* __restrict__ featsbf, ushort_t* __restrict__ attnbf)
{
    __shared__ float alpha_s[200];
    __shared__ float red[8];
    const int b = blockIdx.x;
    const int tid = threadIdx.x;

    const float val = (tid < kN) ? scoresbuf[b * kN + tid] : -1e30f;
    float m = val;
#pragma unroll
    for (int off = 32; off; off >>= 1) m = fmaxf(m, __shfl_down(m, off));
    if ((tid & 63) == 0) red[tid >> 6] = m;
    __syncthreads();
    m = fmaxf(fmaxf(red[0], red[1]), fmaxf(red[2], red[3]));
    const float e = (tid < kN) ? __expf(val - m) : 0.f;
    float s = e;
#pragma unroll
    for (int off = 32; off; off >>= 1) s += __shfl_down(s, off);
    if ((tid & 63) == 0) red[4 + (tid >> 6)] = s;
    __syncthreads();
    s = red[4] + red[5] + red[6] + red[7];
    if (tid < kN) alpha_s[tid] = e * (1.f / s);
    __syncthreads();

    if (BF) {
        const int f0 = blockIdx.y * 512 + tid * 2;
        const ushort_t* fb = featsbf + (size_t)b * kN * 1024 + f0;
        float a0 = 0.f, a1 = 0.f;
#pragma unroll 4
        for (int n = 0; n < kN; ++n) {
            const uint_t u = *(const uint_t*)(fb + (size_t)n * 1024);
            a0 += alpha_s[n] * __uint_as_float(u << 16);
            a1 += alpha_s[n] * __uint_as_float(u & 0xffff0000u);
        }
        uint_t o = ((uint_t)f2bf(a1) << 16) | (uint_t)f2bf(a0);
        *(uint_t*)&attnbf[(size_t)b * 1024 + f0] = o;
    } else {
        const int f = blockIdx.y * 256 + tid;
        const float* fb = featsf + (size_t)b * kN * 1024 + f;
        float a = 0.f;
#pragma unroll 4
        for (int n = 0; n < kN; ++n) a += alpha_s[n] * fb[(size_t)n * 1024];
        attnbf[(size_t)b * 1024 + f] = f2bf(a);
    }
}

// ---------------------------------------------------------------------------
// Kernel C: gates0 = [attn|emb_t](bf16) @ W0cat[4096,2048] + Ypart + bias
//           -> cell0 -> h(bf16, in-place), c(fp32, in-place).
// Tile 128M x 64N, BK=32, grid 64.
// ---------------------------------------------------------------------------
__global__ __launch_bounds__(256) void gatesC(
    const ushort_t* __restrict__ attnbf, const ushort_t* __restrict__ embbf,
    const ushort_t* __restrict__ W0cat, const float* __restrict__ Ypart,
    const float* __restrict__ bih0, const float* __restrict__ bhh0,
    float* __restrict__ cbuf, ushort_t* __restrict__ hbf, int tstep)
{
    __shared__ ushort_t xs[128 * 40];
    __shared__ ushort_t wsB[64 * 40];
    __shared__ float eps[128][65];

    const int tid = threadIdx.x;
    const int n0 = blockIdx.x * 64;
    const int lane = tid & 63, w = tid >> 6;
    const int wm = (w & 1) * 64, wn = (w >> 1) * 32;
    const int lr = lane & 15, quad = lane >> 4;

    f32x4 acc[4][2];
#pragma unroll
    for (int i = 0; i < 4; ++i) {
        acc[i][0] = (f32x4){0.f, 0.f, 0.f, 0.f};
        acc[i][1] = (f32x4){0.f, 0.f, 0.f, 0.f};
    }

    for (int k0 = 0; k0 < 2048; k0 += 32) {
#pragma unroll
        for (int it = 0; it < 2; ++it) {
            const int q = it * 256 + tid;
            const int row = q >> 2, kc = (q & 3) * 8;
            const ushort_t* src = (k0 < 1024)
                ? (attnbf + (size_t)row * 1024 + k0 + kc)
                : (embbf + ((size_t)row * kT + tstep) * 1024 + (k0 - 1024) + kc);
            *(uint4*)&xs[row * 40 + kc] = *(const uint4*)src;
        }
        {
            const int row = tid >> 2, kc = (tid & 3) * 8;
            *(uint4*)&wsB[row * 40 + kc] =
                *(const uint4*)&W0cat[(size_t)(n0 + row) * 2048 + k0 + kc];
        }
        __syncthreads();
        bf16x8 af[4], bb[2];
#pragma unroll
        for (int mf = 0; mf < 4; ++mf)
            af[mf] = *(const bf16x8*)&xs[(wm + mf * 16 + lr) * 40 + quad * 8];
#pragma unroll
        for (int nf = 0; nf < 2; ++nf)
            bb[nf] = *(const bf16x8*)&wsB[(wn + nf * 16 + lr) * 40 + quad * 8];
#pragma unroll
        for (int mf = 0; mf < 4; ++mf)
#pragma unroll
            for (int nf = 0; nf < 2; ++nf)
                acc[mf][nf] = __builtin_amdgcn_mfma_f32_16x16x32_bf16(
                    af[mf], bb[nf], acc[mf][nf], 0, 0, 0);
        __syncthreads();
    }

#pragma unroll
    for (int mf = 0; mf < 4; ++mf)
#pragma unroll
        for (int nf = 0; nf < 2; ++nf)
#pragma unroll
            for (int r = 0; r < 4; ++r)
                eps[wm + mf * 16 + quad * 4 + r][wn + nf * 16 + lr] = acc[mf][nf][r];
    __syncthreads();

#pragma unroll
    for (int i = 0; i < 8; ++i) {
        const int cid = i * 256 + tid;
        const int b = cid & 127, ulc = cid >> 7;
        const int u = (n0 >> 2) + ulc;
        const int jb = n0 + ulc * 4;
        const float* yp = Ypart + (size_t)b * 4096 + jb;
        const float iv = fsigmoid(eps[b][ulc * 4 + 0] + yp[0] + bih0[u]        + bhh0[u]);
        const float fv = fsigmoid(eps[b][ulc * 4 + 1] + yp[1] + bih0[1024 + u] + bhh0[1024 + u]);
        const float gv = ftanh   (eps[b][ulc * 4 + 2] + yp[2] + bih0[2048 + u] + bhh0[2048 + u]);
        const float ov = fsigmoid(eps[b][ulc * 4 + 3] + yp[3] + bih0[3072 + u] + bhh0[3072 + u]);
        const float cp = cbuf[(size_t)b * 1024 + u];
        const float cn = fv * cp + iv * gv;
        cbuf[(size_t)b * 1024 + u] = cn;
        hbf[(size_t)b * 1024 + u] = f2bf(ov * ftanh(cn));
    }
}

// ---------------------------------------------------------------------------
extern "C" void kernel_launch(void* const* d_in, const int* in_sizes, int n_in,
                              void* d_out, int out_size, void* d_ws, size_t ws_size,
                              hipStream_t stream)
{
    const float* feats = (const float*)d_in[0];
    const float* emb   = (const float*)d_in[1];
    const float* Wf    = (const float*)d_in[2];
    const float* Wh    = (const float*)d_in[3];
    const float* b_att = (const float*)d_in[4];
    const float* vvec  = (const float*)d_in[5];
    const float* Wih0  = (const float*)d_in[6];
    const float* Whh0  = (const float*)d_in[7];
    const float* bih0  = (const float*)d_in[8];
    const float* bhh0  = (const float*)d_in[9];
    const float* Wih1  = (const float*)d_in[10];
    const float* Whh1  = (const float*)d_in[11];
    const float* bih1  = (const float*)d_in[12];
    const float* bhh1  = (const float*)d_in[13];
    float* out = (float*)d_out;

    // workspace layout (ushort units first, then fp32)
    ushort_t* fprojbf = (ushort_t*)d_ws;                       // 25088*1024
    ushort_t* embbf   = fprojbf + (size_t)25088 * 1024;        // 4096*1024
    ushort_t* Wbig    = embbf   + (size_t)4096 * 1024;         // 9216*1024
    ushort_t* W0cat   = Wbig    + (size_t)9216 * 1024;         // 4096*2048
    ushort_t* WfT     = W0cat   + (size_t)4096 * 2048;         // 1024*1024
    ushort_t* hbf     = WfT     + (size_t)1024 * 1024;         // 128*1024
    ushort_t* attnbf  = hbf     + (size_t)128 * 1024;          // 128*1024
    float* hwh        = (float*)(attnbf + (size_t)128 * 1024); // 128*1024
    float* Ypart      = hwh   + (size_t)128 * 1024;            // 128*4096
    float* cbuf       = Ypart + (size_t)128 * 4096;            // 128*1024
    float* scoresbuf  = cbuf  + (size_t)128 * 1024;            // 128*196
    ushort_t* featsbf = (ushort_t*)(scoresbuf + 128 * 196);    // 25088*1024 (optional)

    const size_t need_full = 152668160;  // bytes incl. featsbf
    const bool use_bf = (ws_size >= need_full);

    // zero h, c
    hipMemsetAsync(hbf, 0, sizeof(ushort_t) * 128 * 1024, stream);
    hipMemsetAsync(cbuf, 0, sizeof(float) * 128 * 1024, stream);

    // pre-pass packs
    wf_transpose<<<dim3(16, 16), 256, 0, stream>>>(Wf, WfT);
    wf_transpose<<<dim3(16, 16), 256, 0, stream>>>(Wh, Wbig);  // rows 0..1023
    pack_whh0<<<4096, 256, 0, stream>>>(Whh0, Wbig);
    pack_w1sum<<<4096, 256, 0, stream>>>(Wih1, Whh1, Wbig);
    pack_w0cat<<<8192, 256, 0, stream>>>(Wih0, W0cat);
    cast_bf<<<4096, 256, 0, stream>>>(emb, embbf);
    if (use_bf) cast_bf<<<25088, 256, 0, stream>>>(feats, featsbf);

    // fproj (bf16) = feats @ Wf + b_att
    fproj_mfma<<<dim3(196, 8), 256, 0, stream>>>(feats, WfT, b_att, fprojbf);

    for (int t = 0; t < kT; ++t) {
        hgemm_A<<<144, 256, 0, stream>>>(hbf, Wbig, cbuf, bih1, bhh1,
                                         hwh, Ypart, out, t);
        scores_kernel<<<dim3(128, 7), 256, 0, stream>>>(fprojbf, hwh, vvec, scoresbuf);
        if (use_bf)
            attn_kernel<1><<<dim3(128, 2), 256, 0, stream>>>(scoresbuf, feats, featsbf, attnbf);
        else
            attn_kernel<0><<<dim3(128, 4), 256, 0, stream>>>(scoresbuf, feats, featsbf, attnbf);
        gatesC<<<64, 256, 0, stream>>>(attnbf, embbf, W0cat, Ypart,
                                       bih0, bhh0, cbuf, hbf, t);
    }
    // final cell1 for t=31 (uses h_32, c_32)
    hgemm_A<<<144, 256, 0, stream>>>(hbf, Wbig, cbuf, bih1, bhh1,
                                     hwh, Ypart, out, kT);

    (void)in_sizes; (void)n_in; (void)out_size; (void)ws_size;
}